// Round 7
// baseline (149.521 us; speedup 1.0000x reference)
//
#include <hip/hip_runtime.h>
#include <stdint.h>

// Problem constants (B=8, K=4, N=131072)
#define NTOT      4194304LL   // B*K*N
#define CHUNK     2048        // elements per block
#define NBLK      2048        // NTOT / CHUNK
#define NEG_PAD   (-1000.0f)
#define NEG_IDLE  (-100000000.0f)

typedef unsigned long long u64;
typedef float float4u __attribute__((ext_vector_type(4), aligned(4)));   // dwordx4, 4-B align
typedef float float3u __attribute__((ext_vector_type(3), aligned(4)));   // dwordx3
typedef float float4a __attribute__((ext_vector_type(4), aligned(16)));

// ---------------------------------------------------------------------------
// K1: read masks ONCE (int32 bools); emit per-8-element compressed bitmasks
// (u16: sbits | abits<<8) and per-block packed totals (surface | air<<32).
// ---------------------------------------------------------------------------
__global__ __launch_bounds__(256, 8) void count_kernel(
    const int* __restrict__ ms, const int* __restrict__ ma,
    unsigned short* __restrict__ cmp, u64* __restrict__ totals)
{
    const int t = threadIdx.x, lane = t & 63, wave = t >> 6;
    const unsigned bid = blockIdx.x;
    const long long base = (long long)bid * CHUNK;

    const int4* ms4 = (const int4*)(ms + base);
    const int4* ma4 = (const int4*)(ma + base);
    int4 s0 = ms4[2 * t], s1 = ms4[2 * t + 1];
    int4 a0 = ma4[2 * t], a1 = ma4[2 * t + 1];
    unsigned sbits = (unsigned)(s0.x != 0)        | ((unsigned)(s0.y != 0) << 1)
                   | ((unsigned)(s0.z != 0) << 2) | ((unsigned)(s0.w != 0) << 3)
                   | ((unsigned)(s1.x != 0) << 4) | ((unsigned)(s1.y != 0) << 5)
                   | ((unsigned)(s1.z != 0) << 6) | ((unsigned)(s1.w != 0) << 7);
    unsigned abits = (unsigned)(a0.x != 0)        | ((unsigned)(a0.y != 0) << 1)
                   | ((unsigned)(a0.z != 0) << 2) | ((unsigned)(a0.w != 0) << 3)
                   | ((unsigned)(a1.x != 0) << 4) | ((unsigned)(a1.y != 0) << 5)
                   | ((unsigned)(a1.z != 0) << 6) | ((unsigned)(a1.w != 0) << 7);

    cmp[bid * 256u + (unsigned)t] = (unsigned short)(sbits | (abits << 8));

    unsigned cnt = __popc(sbits) | (__popc(abits) << 16);
    #pragma unroll
    for (int o = 32; o; o >>= 1) cnt += __shfl_down(cnt, o, 64);
    __shared__ unsigned lds[4];
    if (lane == 0) lds[wave] = cnt;
    __syncthreads();
    if (t == 0) {
        unsigned tot = lds[0] + lds[1] + lds[2] + lds[3];
        totals[bid] = (u64)(tot & 0xffffu) | ((u64)(tot >> 16) << 32);
    }
}

// ---------------------------------------------------------------------------
// K2: flattened single-tile expand. 3 barriers total (2 scan + 1 tile).
// All gathers (4 ls/la windows + 8 rgb dwordx3 rounds) issued in one
// unrolled region for max memory-level parallelism; 24 KB rgb LDS tile is
// bulk-copied as coalesced float4 at the end. ls/la: thread owns 4
// consecutive elements; one unaligned dwordx4 window covers its (<=4,
// consecutive) ranks; per-element select in-register; float4 stores.
// ---------------------------------------------------------------------------
__global__ __launch_bounds__(256, 4) void expand_kernel(
    const float* __restrict__ rgb, const float* __restrict__ lsurf,
    const float* __restrict__ lair, const float* __restrict__ idle,
    const unsigned short* __restrict__ cmp, const u64* __restrict__ totals,
    unsigned rgb_max, unsigned ts_max, unsigned ta_max,
    float* __restrict__ out_rgb, float* __restrict__ out_ls, float* __restrict__ out_la)
{
    __shared__ unsigned wsum[4];
    __shared__ u64 wacc[4];
    __shared__ unsigned packLDS[256];   // u16 pack per 8 elements
    __shared__ unsigned prefLDS[256];   // packed exclusive prefix (s | a<<16)
    __shared__ float    rgbLDS[6144];   // 24 KB: full block tile (2048*3)

    const int t = threadIdx.x, lane = t & 63, wave = t >> 6;
    const unsigned bid = blockIdx.x;
    const long long base = (long long)bid * CHUNK;

    // --- independent loads first ---
    unsigned pk = cmp[bid * 256u + (unsigned)t];
    u64 acc = 0;
    #pragma unroll
    for (int j = 0; j < 8; ++j) {
        unsigned idx = (unsigned)t * 8u + (unsigned)j;
        acc += (idx < bid) ? totals[idx] : 0ULL;
    }
    const float idle_v = idle[(int)(base >> 17)];     // chunk lies in one (b,k) row

    packLDS[t] = pk;
    unsigned cnt = __popc(pk & 0xffu) | (__popc(pk >> 8) << 16);

    unsigned x = cnt;
    #pragma unroll
    for (int o = 1; o < 64; o <<= 1) {
        unsigned y = __shfl_up(x, o, 64);
        if (lane >= o) x += y;
    }
    if (lane == 63) wsum[wave] = x;
    #pragma unroll
    for (int o = 32; o; o >>= 1) acc += __shfl_down(acc, o, 64);
    if (lane == 0) wacc[wave] = acc;
    __syncthreads();
    unsigned pre = (wave > 0 ? wsum[0] : 0u) + (wave > 1 ? wsum[1] : 0u)
                 + (wave > 2 ? wsum[2] : 0u);
    prefLDS[t] = pre + x - cnt;                       // per-pack exclusive (packed)
    u64 basesum = wacc[0] + wacc[1] + wacc[2] + wacc[3];
    const unsigned excS = (unsigned)(basesum & 0xffffffffULL);
    const unsigned excA = (unsigned)(basesum >> 32);
    __syncthreads();

    const float alive     = 1.0f - idle_v;
    const float idle_term = idle_v * NEG_IDLE;
    const int  sub = t >> 3, b = t & 7;
    const unsigned bm = (1u << b) - 1u;
    const int  hp = t >> 1;
    const unsigned nib = (unsigned)(t & 1) * 4u;
    const unsigned nm  = (1u << nib) - 1u;

    // ---- ls/la: issue both half-windows' gathers up front ----
    unsigned r0s[2], r0a[2], rbs[2], rba[2], sb[2], ab[2];
    float4u Ws[2], Wa[2];
    #pragma unroll
    for (int h = 0; h < 2; ++h) {
        const int p = h * 128 + hp;
        unsigned w  = packLDS[p];
        unsigned pv = prefLDS[p];
        unsigned ws = w & 0xffu, wag = (w >> 8) & 0xffu;
        r0s[h] = excS + (pv & 0xffffu) + __popc(ws & nm);
        r0a[h] = excA + (pv >> 16)     + __popc(wag & nm);
        sb[h] = (ws >> nib) & 0xFu;
        ab[h] = (wag >> nib) & 0xFu;
        rbs[h] = r0s[h] < ts_max - 3u ? r0s[h] : ts_max - 3u;
        rba[h] = r0a[h] < ta_max - 3u ? r0a[h] : ta_max - 3u;
        Ws[h] = *(const float4u*)(lsurf + rbs[h]);
        Wa[h] = *(const float4u*)(lair  + rba[h]);
    }

    // ---- rgb: 8 gather rounds into the 24 KB tile ----
    #pragma unroll
    for (int g = 0; g < 8; ++g) {
        const int p = (g << 5) + sub;
        unsigned w  = packLDS[p];
        unsigned pv = prefLDS[p];
        unsigned rs = excS + (pv & 0xffffu) + __popc(w & bm);
        const int li = g * 768 + 3 * t;               // banks 3t%32: 2-way, free
        if ((w >> b) & 1u) {
            unsigned pr = rs < rgb_max ? rs : rgb_max;   // _expand's clip
            float3u v = *(const float3u*)(rgb + 3LL * pr);
            rgbLDS[li]     = v.x * alive;
            rgbLDS[li + 1] = v.y * alive;
            rgbLDS[li + 2] = v.z * alive;
        } else {
            rgbLDS[li] = 0.f; rgbLDS[li + 1] = 0.f; rgbLDS[li + 2] = 0.f;
        }
    }

    // ---- ls/la: select + coalesced float4 stores ----
    #pragma unroll
    for (int h = 0; h < 2; ++h) {
        float lsv[4], lav[4];
        #pragma unroll
        for (int j = 0; j < 4; ++j) {
            unsigned mj = (1u << j) - 1u;
            unsigned rj = r0s[h] + __popc(sb[h] & mj);
            unsigned cs = (rj < ts_max ? rj : ts_max) - rbs[h];   // 0..3
            float vs = cs == 0 ? Ws[h].x : cs == 1 ? Ws[h].y : cs == 2 ? Ws[h].z : Ws[h].w;
            lsv[j] = ((sb[h] >> j) & 1u) ? vs * alive + idle_term : NEG_PAD;
            unsigned rk = r0a[h] + __popc(ab[h] & mj);
            unsigned ca = (rk < ta_max ? rk : ta_max) - rba[h];
            float va = ca == 0 ? Wa[h].x : ca == 1 ? Wa[h].y : ca == 2 ? Wa[h].z : Wa[h].w;
            lav[j] = ((ab[h] >> j) & 1u) ? va * alive + idle_term : NEG_PAD;
        }
        const long long eb = base + h * 1024 + 4 * t;  // 16-B aligned
        float4a vls; vls.x = lsv[0]; vls.y = lsv[1]; vls.z = lsv[2]; vls.w = lsv[3];
        float4a vla; vla.x = lav[0]; vla.y = lav[1]; vla.z = lav[2]; vla.w = lav[3];
        *(float4a*)(out_ls + eb) = vls;
        *(float4a*)(out_la + eb) = vla;
    }

    __syncthreads();                                  // tile complete
    // bulk copy 24 KB tile -> global, lane-consecutive float4 (coalesced)
    float4a* dst = (float4a*)(out_rgb + 3 * base);
    const float4a* src = (const float4a*)rgbLDS;
    #pragma unroll
    for (int q = 0; q < 6; ++q)
        dst[t + 256 * q] = src[t + 256 * q];
}

extern "C" void kernel_launch(void* const* d_in, const int* in_sizes, int n_in,
                              void* d_out, int out_size, void* d_ws, size_t ws_size,
                              hipStream_t stream)
{
    const float* rgb   = (const float*)d_in[0];
    const float* lsurf = (const float*)d_in[1];
    const float* lair  = (const float*)d_in[2];
    const float* idle  = (const float*)d_in[3];
    const int*   ms    = (const int*)d_in[4];   // bool -> int32 per harness contract
    const int*   ma    = (const int*)d_in[5];

    unsigned rgb_max = (unsigned)(in_sizes[0] / 3 - 1);
    unsigned ts_max  = (unsigned)(in_sizes[1] - 1);
    unsigned ta_max  = (unsigned)(in_sizes[2] - 1);

    float* out     = (float*)d_out;
    float* out_rgb = out;                  // (B,K,N,3)
    float* out_ls  = out + NTOT * 3;       // (B,K,N,1)
    float* out_la  = out_ls + NTOT;        // (B,K,N,1)

    // Workspace: totals (16 KB) then compressed masks (1 MB); both fully
    // rewritten by K1 every launch -> no init needed despite 0xAA poison.
    u64* totals = (u64*)d_ws;
    unsigned short* cmp = (unsigned short*)((char*)d_ws + 16384);

    count_kernel<<<NBLK, 256, 0, stream>>>(ms, ma, cmp, totals);
    expand_kernel<<<NBLK, 256, 0, stream>>>(rgb, lsurf, lair, idle, cmp, totals,
                                            rgb_max, ts_max, ta_max,
                                            out_rgb, out_ls, out_la);
}

// Round 8
// 148.202 us; speedup vs baseline: 1.0089x; 1.0089x over previous
//
#include <hip/hip_runtime.h>
#include <stdint.h>

// Problem constants (B=8, K=4, N=131072)
#define NTOT      4194304LL   // B*K*N
#define CHUNK     2048        // elements per block
#define NBLK      2048        // NTOT / CHUNK
#define NEG_PAD   (-1000.0f)
#define NEG_IDLE  (-100000000.0f)

typedef unsigned long long u64;
typedef float float4u __attribute__((ext_vector_type(4), aligned(4)));   // dwordx4, 4-B align
typedef float float3u __attribute__((ext_vector_type(3), aligned(4)));   // dwordx3, loads 12 B
typedef float float4a __attribute__((ext_vector_type(4), aligned(16)));

// ---------------------------------------------------------------------------
// K1: read masks ONCE (int32 bools); emit per-8-element compressed bitmasks
// (u16: sbits | abits<<8) and per-block packed totals (surface | air<<32).
// Measured at ~6 us, vs 5.2 us BW floor for the 33.5 MB mask read.
// ---------------------------------------------------------------------------
__global__ __launch_bounds__(256, 8) void count_kernel(
    const int* __restrict__ ms, const int* __restrict__ ma,
    unsigned short* __restrict__ cmp, u64* __restrict__ totals)
{
    const int t = threadIdx.x, lane = t & 63, wave = t >> 6;
    const unsigned bid = blockIdx.x;
    const long long base = (long long)bid * CHUNK;

    const int4* ms4 = (const int4*)(ms + base);
    const int4* ma4 = (const int4*)(ma + base);
    int4 s0 = ms4[2 * t], s1 = ms4[2 * t + 1];
    int4 a0 = ma4[2 * t], a1 = ma4[2 * t + 1];
    unsigned sbits = (unsigned)(s0.x != 0)        | ((unsigned)(s0.y != 0) << 1)
                   | ((unsigned)(s0.z != 0) << 2) | ((unsigned)(s0.w != 0) << 3)
                   | ((unsigned)(s1.x != 0) << 4) | ((unsigned)(s1.y != 0) << 5)
                   | ((unsigned)(s1.z != 0) << 6) | ((unsigned)(s1.w != 0) << 7);
    unsigned abits = (unsigned)(a0.x != 0)        | ((unsigned)(a0.y != 0) << 1)
                   | ((unsigned)(a0.z != 0) << 2) | ((unsigned)(a0.w != 0) << 3)
                   | ((unsigned)(a1.x != 0) << 4) | ((unsigned)(a1.y != 0) << 5)
                   | ((unsigned)(a1.z != 0) << 6) | ((unsigned)(a1.w != 0) << 7);

    cmp[bid * 256u + (unsigned)t] = (unsigned short)(sbits | (abits << 8));

    unsigned cnt = __popc(sbits) | (__popc(abits) << 16);
    #pragma unroll
    for (int o = 32; o; o >>= 1) cnt += __shfl_down(cnt, o, 64);
    __shared__ unsigned lds[4];
    if (lane == 0) lds[wave] = cnt;
    __syncthreads();
    if (t == 0) {
        unsigned tot = lds[0] + lds[1] + lds[2] + lds[3];
        totals[bid] = (u64)(tot & 0xffffu) | ((u64)(tot >> 16) << 32);
    }
}

// ---------------------------------------------------------------------------
// K2 (best-measured variant, R6): per-pack prefixes via one block scan;
// block base via predicated sum of the 16 KB totals array (LLC-hot).
// rgb: per-element dwordx3 gathers into a 12 KB LDS tile per half,
// bulk-copied as coalesced float4 (fixes R4's 4x store amplification).
// ls/la: thread owns 4 consecutive elements; ONE unaligned dwordx4 window
// covers its (consecutive) active ranks; in-register select; float4 stores.
// (256,6): 12.3 KB LDS x6 = 74 KB/CU, 24 waves/CU. Measured 147.9 total.
// ---------------------------------------------------------------------------
__global__ __launch_bounds__(256, 6) void expand_kernel(
    const float* __restrict__ rgb, const float* __restrict__ lsurf,
    const float* __restrict__ lair, const float* __restrict__ idle,
    const unsigned short* __restrict__ cmp, const u64* __restrict__ totals,
    unsigned rgb_max, unsigned ts_max, unsigned ta_max,
    float* __restrict__ out_rgb, float* __restrict__ out_ls, float* __restrict__ out_la)
{
    __shared__ unsigned wsum[4];
    __shared__ u64 wacc[4];
    __shared__ unsigned packLDS[256];   // u16 pack per 8 elements
    __shared__ unsigned prefLDS[256];   // packed exclusive prefix (s | a<<16)
    __shared__ float    rgbLDS[3072];   // 12 KB: 4 rounds of 256*3 floats

    const int t = threadIdx.x, lane = t & 63, wave = t >> 6;
    const unsigned bid = blockIdx.x;
    const long long base = (long long)bid * CHUNK;

    // --- independent loads first ---
    unsigned pk = cmp[bid * 256u + (unsigned)t];
    u64 acc = 0;
    #pragma unroll
    for (int j = 0; j < 8; ++j) {
        unsigned idx = (unsigned)t * 8u + (unsigned)j;
        acc += (idx < bid) ? totals[idx] : 0ULL;
    }
    const float idle_v = idle[(int)(base >> 17)];     // chunk lies in one (b,k) row

    packLDS[t] = pk;
    unsigned cnt = __popc(pk & 0xffu) | (__popc(pk >> 8) << 16);

    unsigned x = cnt;
    #pragma unroll
    for (int o = 1; o < 64; o <<= 1) {
        unsigned y = __shfl_up(x, o, 64);
        if (lane >= o) x += y;
    }
    if (lane == 63) wsum[wave] = x;
    #pragma unroll
    for (int o = 32; o; o >>= 1) acc += __shfl_down(acc, o, 64);
    if (lane == 0) wacc[wave] = acc;
    __syncthreads();
    unsigned pre = (wave > 0 ? wsum[0] : 0u) + (wave > 1 ? wsum[1] : 0u)
                 + (wave > 2 ? wsum[2] : 0u);
    prefLDS[t] = pre + x - cnt;                       // per-pack exclusive (packed)
    u64 basesum = wacc[0] + wacc[1] + wacc[2] + wacc[3];
    const unsigned excS = (unsigned)(basesum & 0xffffffffULL);
    const unsigned excA = (unsigned)(basesum >> 32);
    __syncthreads();

    const float alive     = 1.0f - idle_v;
    const float idle_term = idle_v * NEG_IDLE;
    const int  sub = t >> 3, b = t & 7;
    const unsigned bm = (1u << b) - 1u;
    const int  hp = t >> 1;                // pack within half for ls/la ownership
    const unsigned nib = (unsigned)(t & 1) * 4u;
    const unsigned nm  = (1u << nib) - 1u;

    #pragma unroll
    for (int h = 0; h < 2; ++h) {
        // ---- rgb: 4 rounds of 256, one dwordx3 gather each, into LDS tile ----
        #pragma unroll
        for (int r = 0; r < 4; ++r) {
            const int g = h * 4 + r;
            const int p = (g << 5) + sub;
            unsigned w  = packLDS[p];
            unsigned pv = prefLDS[p];
            unsigned rs = excS + (pv & 0xffffu) + __popc(w & bm);
            const int li = r * 768 + 3 * t;           // banks 3t%32: 2-way, free
            if ((w >> b) & 1u) {
                unsigned pr = rs < rgb_max ? rs : rgb_max;   // _expand's clip
                float3u v = *(const float3u*)(rgb + 3LL * pr);
                rgbLDS[li]     = v.x * alive;
                rgbLDS[li + 1] = v.y * alive;
                rgbLDS[li + 2] = v.z * alive;
            } else {
                rgbLDS[li] = 0.f; rgbLDS[li + 1] = 0.f; rgbLDS[li + 2] = 0.f;
            }
        }
        // ---- ls/la: 4 consecutive elements, window gather + select ----
        {
            const int p = h * 128 + hp;
            unsigned w  = packLDS[p];
            unsigned pv = prefLDS[p];
            unsigned ws = w & 0xffu, wa = (w >> 8) & 0xffu;
            unsigned r0s = excS + (pv & 0xffffu) + __popc(ws & nm);
            unsigned r0a = excA + (pv >> 16)     + __popc(wa & nm);
            unsigned sb = (ws >> nib) & 0xFu;
            unsigned ab = (wa >> nib) & 0xFu;
            unsigned rbs = r0s < ts_max - 3u ? r0s : ts_max - 3u;
            unsigned rba = r0a < ta_max - 3u ? r0a : ta_max - 3u;
            float4u Ws = *(const float4u*)(lsurf + rbs);   // covers ranks rbs..rbs+3
            float4u Wa = *(const float4u*)(lair  + rba);
            float lsv[4], lav[4];
            #pragma unroll
            for (int j = 0; j < 4; ++j) {
                unsigned mj = (1u << j) - 1u;
                unsigned rj = r0s + __popc(sb & mj);
                unsigned cs = (rj < ts_max ? rj : ts_max) - rbs;   // 0..3
                float vs = cs == 0 ? Ws.x : cs == 1 ? Ws.y : cs == 2 ? Ws.z : Ws.w;
                lsv[j] = ((sb >> j) & 1u) ? vs * alive + idle_term : NEG_PAD;
                unsigned rk = r0a + __popc(ab & mj);
                unsigned ca = (rk < ta_max ? rk : ta_max) - rba;
                float va = ca == 0 ? Wa.x : ca == 1 ? Wa.y : ca == 2 ? Wa.z : Wa.w;
                lav[j] = ((ab >> j) & 1u) ? va * alive + idle_term : NEG_PAD;
            }
            const long long eb = base + h * 1024 + 4 * t;  // 16-B aligned
            float4a vls; vls.x = lsv[0]; vls.y = lsv[1]; vls.z = lsv[2]; vls.w = lsv[3];
            float4a vla; vla.x = lav[0]; vla.y = lav[1]; vla.z = lav[2]; vla.w = lav[3];
            *(float4a*)(out_ls + eb) = vls;
            *(float4a*)(out_la + eb) = vla;
        }
        __syncthreads();                              // rgb tile complete
        float4a* dst = (float4a*)(out_rgb + 3 * base) + h * 768;
        const float4a* src = (const float4a*)rgbLDS;
        dst[t]       = src[t];
        dst[t + 256] = src[t + 256];
        dst[t + 512] = src[t + 512];
        __syncthreads();                              // tile reusable
    }
}

extern "C" void kernel_launch(void* const* d_in, const int* in_sizes, int n_in,
                              void* d_out, int out_size, void* d_ws, size_t ws_size,
                              hipStream_t stream)
{
    const float* rgb   = (const float*)d_in[0];
    const float* lsurf = (const float*)d_in[1];
    const float* lair  = (const float*)d_in[2];
    const float* idle  = (const float*)d_in[3];
    const int*   ms    = (const int*)d_in[4];   // bool -> int32 per harness contract
    const int*   ma    = (const int*)d_in[5];

    unsigned rgb_max = (unsigned)(in_sizes[0] / 3 - 1);
    unsigned ts_max  = (unsigned)(in_sizes[1] - 1);
    unsigned ta_max  = (unsigned)(in_sizes[2] - 1);

    float* out     = (float*)d_out;
    float* out_rgb = out;                  // (B,K,N,3)
    float* out_ls  = out + NTOT * 3;       // (B,K,N,1)
    float* out_la  = out_ls + NTOT;        // (B,K,N,1)

    // Workspace: totals (16 KB) then compressed masks (1 MB); both fully
    // rewritten by K1 every launch -> no init needed despite 0xAA poison.
    u64* totals = (u64*)d_ws;
    unsigned short* cmp = (unsigned short*)((char*)d_ws + 16384);

    count_kernel<<<NBLK, 256, 0, stream>>>(ms, ma, cmp, totals);
    expand_kernel<<<NBLK, 256, 0, stream>>>(rgb, lsurf, lair, idle, cmp, totals,
                                            rgb_max, ts_max, ta_max,
                                            out_rgb, out_ls, out_la);
}